// Round 4
// baseline (751.184 us; speedup 1.0000x reference)
//
#include <hip/hip_runtime.h>

// ExplodedLogit: out (512, 1 + 512*512) fp32.
//   scores = x @ W.T + b            (512,)
//   idx    = argmax(scores)
//   out[i][0]             = scores[i]
//   out[i][1 + r*512 + j] = scores[i] * (j==idx ? MASK_VAL : 1.0f)
//
// R7: MEASUREMENT ROUND. Identical to R6 except fill_kernel is launched 3x
// (idempotent). dur_us - 542.6 ~= 2 x fill_duration. Purpose: the top-5
// rocprof table is swamped by >=5 poison fillBuffer dispatches (340+ us), so
// the fill's own duration has never been observed. This disambiguates:
//  World A: fill ~150us (3.5 TB/s)  -> dur ~830-860 -> fill still improvable
//           or at kernel-store ceiling; poison WRITE_SIZE honest.
//  World B: fill ~88us (6 TB/s)     -> dur ~705-725 -> ~100us of non-fill
//           overhead is the real target; poison WRITE_SIZE is 4x-inflated
//           (it is EXACTLY 4x out_bytes incl. the odd +1 column).

#define TRACKS 512
#define FEATURES 256
#define ROWSTRIDE 262145LL          // 1 + 512*512
#define MASK_VAL (-105.918914f)     // float32(log(1e-46))
#define BPR 64                      // blocks per row -> 32768 blocks total

typedef float vf4 __attribute__((ext_vector_type(4)));

// ---- kernel 1: one wave per row dot-product ----
__global__ __launch_bounds__(64) void scores_kernel(
    const float* __restrict__ x, const float* __restrict__ W,
    const float* __restrict__ b, float* __restrict__ scores) {
  int row = blockIdx.x;
  int lane = threadIdx.x;  // 0..63
  const float4* xr = (const float4*)(x + row * FEATURES);
  const float4* wr = (const float4*)W;
  float4 xv = xr[lane];
  float4 wv = wr[lane];
  float s = xv.x * wv.x + xv.y * wv.y + xv.z * wv.z + xv.w * wv.w;
#pragma unroll
  for (int off = 32; off; off >>= 1) s += __shfl_down(s, off);
  if (lane == 0) scores[row] = s + b[0];
}

// ---- kernel 2: argmax + col-0 + unaligned row-edge floats ----
__global__ __launch_bounds__(512) void argmax_edges_kernel(
    const float* __restrict__ scores, int* __restrict__ idx_out,
    float* __restrict__ out) {
  __shared__ float svals[TRACKS];
  __shared__ int sidx[TRACKS];
  int t = threadIdx.x;
  float s = scores[t];
  svals[t] = s;
  sidx[t] = t;
  __syncthreads();
  for (int off = 256; off; off >>= 1) {
    if (t < off) {
      float v2 = svals[t + off];
      int i2 = sidx[t + off];
      if (v2 > svals[t] || (v2 == svals[t] && i2 < sidx[t])) {
        svals[t] = v2;
        sidx[t] = i2;
      }
    }
    __syncthreads();
  }
  if (t == 0) idx_out[0] = sidx[0];
  int idx = sidx[0];  // valid: last loop iteration ended with __syncthreads

  float sm = s * MASK_VAL;
  long long F = (long long)t * ROWSTRIDE;
  out[F] = s;  // column 0
  long long A = (F + 4) & ~3LL;
  for (long long p = F + 1; p < A; ++p) {
    int j = (int)(p - F - 1) & 511;
    out[p] = (j == idx) ? sm : s;
  }
  long long T = (F + ROWSTRIDE) & ~3LL;
  for (long long p = T; p < F + ROWSTRIDE; ++p) {
    int j = (int)(p - F - 1) & 511;
    out[p] = (j == idx) ? sm : s;
  }
}

// ---- kernel 3: pure-store fill of each row's aligned f4 interior ----
__global__ __launch_bounds__(256) void fill_kernel(
    const float* __restrict__ scores, const int* __restrict__ idxp,
    float* __restrict__ out) {
  int row = blockIdx.x >> 6;      // / BPR
  int chunk = blockIdx.x & (BPR - 1);
  int t = threadIdx.x;

  float s = scores[row];          // block-uniform -> scalar load
  int idx = *idxp;                // block-uniform -> scalar load
  float sm = s * MASK_VAL;

  long long F = (long long)row * ROWSTRIDE;
  long long A4 = (F + 4) >> 2;                 // first aligned f4 of interior
  long long T4 = (F + ROWSTRIDE) >> 2;         // one past last aligned f4
  long long p4 = A4 + (long long)chunk * 1024 + t;

  int j0 = (int)((4 * p4 - F - 1) & 511);
  vf4 val;
  val.x = (j0 == idx) ? sm : s;
  val.y = (((j0 + 1) & 511) == idx) ? sm : s;
  val.z = (((j0 + 2) & 511) == idx) ? sm : s;
  val.w = (((j0 + 3) & 511) == idx) ? sm : s;

  vf4* outv = (vf4*)out;
#pragma unroll
  for (int k = 0; k < 4; ++k) {
    long long p = p4 + k * 256;
    if (p < T4) outv[p] = val;   // guard trims <=1 f4 on the last chunk
  }
}

extern "C" void kernel_launch(void* const* d_in, const int* in_sizes, int n_in,
                              void* d_out, int out_size, void* d_ws,
                              size_t ws_size, hipStream_t stream) {
  const float* x = (const float*)d_in[0];
  const float* W = (const float*)d_in[1];
  const float* b = (const float*)d_in[2];
  float* out = (float*)d_out;

  float* scores = (float*)d_ws;              // 512 floats
  int* idx = (int*)((float*)d_ws + TRACKS);  // 1 int

  scores_kernel<<<TRACKS, 64, 0, stream>>>(x, W, b, scores);
  argmax_edges_kernel<<<1, TRACKS, 0, stream>>>(scores, idx, out);
  // 3x fill: idempotent. Extra 2 dispatches exist ONLY to measure
  // fill duration via dur_us delta vs R6 (see header comment).
  fill_kernel<<<TRACKS * BPR, 256, 0, stream>>>(scores, idx, out);
  fill_kernel<<<TRACKS * BPR, 256, 0, stream>>>(scores, idx, out);
  fill_kernel<<<TRACKS * BPR, 256, 0, stream>>>(scores, idx, out);
}

// Round 5
// 694.765 us; speedup vs baseline: 1.0812x; 1.0812x over previous
//
#include <hip/hip_runtime.h>

// ExplodedLogit: out (512, 1 + 512*512) fp32.
//
// R8: MEASUREMENT ROUND 2. R7 established within-probe: R6-fill = 104.3 us
// (5.15 TB/s), base-without-fill = 438.3 us (343 poison + ~95 harness/tiny).
// Open question: R4's flat grid-stride fill measured 513.4 total cross-run
// (29 us faster than R6) - noise or real? This round: same structure as R7
// but the 3x fill is R4's FLAT fill.  fill_flat = (dur - 438.3)/3.
//   ~104 us -> dur ~750: noise; declare roofline next round w/ R6 fill.
//   ~80  us -> dur ~678: real; adopt flat fill single-shot (~518 total).

#define TRACKS 512
#define FEATURES 256
#define ROWSTRIDE 262145            // 1 + 512*512
#define ROWSTRIDE_LL 262145LL
#define MASK_VAL (-105.918914f)     // float32(log(1e-46))

#define TOTAL_F4 33554560u          // 512*262145/4 (exact)
#define FILL_BLOCKS 32768
#define FILL_TPB 256

typedef float vf4 __attribute__((ext_vector_type(4)));

// ---- kernel 1: one wave per row dot-product ----
__global__ __launch_bounds__(64) void scores_kernel(
    const float* __restrict__ x, const float* __restrict__ W,
    const float* __restrict__ b, float* __restrict__ scores) {
  int row = blockIdx.x;
  int lane = threadIdx.x;  // 0..63
  const float4* xr = (const float4*)(x + row * FEATURES);
  const float4* wr = (const float4*)W;
  float4 xv = xr[lane];
  float4 wv = wr[lane];
  float s = xv.x * wv.x + xv.y * wv.y + xv.z * wv.z + xv.w * wv.w;
#pragma unroll
  for (int off = 32; off; off >>= 1) s += __shfl_down(s, off);
  if (lane == 0) scores[row] = s + b[0];
}

// ---- kernel 2: argmax + col-0 + unaligned row-edge floats ----
// (identical to R6/R7; writes duplicated by the flat fill are value-identical)
__global__ __launch_bounds__(512) void argmax_edges_kernel(
    const float* __restrict__ scores, int* __restrict__ idx_out,
    float* __restrict__ out) {
  __shared__ float svals[TRACKS];
  __shared__ int sidx[TRACKS];
  int t = threadIdx.x;
  float s = scores[t];
  svals[t] = s;
  sidx[t] = t;
  __syncthreads();
  for (int off = 256; off; off >>= 1) {
    if (t < off) {
      float v2 = svals[t + off];
      int i2 = sidx[t + off];
      if (v2 > svals[t] || (v2 == svals[t] && i2 < sidx[t])) {
        svals[t] = v2;
        sidx[t] = i2;
      }
    }
    __syncthreads();
  }
  if (t == 0) idx_out[0] = sidx[0];
  int idx = sidx[0];

  float sm = s * MASK_VAL;
  long long F = (long long)t * ROWSTRIDE_LL;
  out[F] = s;  // column 0
  long long A = (F + 4) & ~3LL;
  for (long long p = F + 1; p < A; ++p) {
    int j = (int)(p - F - 1) & 511;
    out[p] = (j == idx) ? sm : s;
  }
  long long T = (F + ROWSTRIDE_LL) & ~3LL;
  for (long long p = T; p < F + ROWSTRIDE_LL; ++p) {
    int j = (int)(p - F - 1) & 511;
    out[p] = (j == idx) ? sm : s;
  }
}

// ---- kernel 3: R4's flat grid-stride fill of the whole buffer ----
__global__ __launch_bounds__(FILL_TPB) void fill_flat(
    const float* __restrict__ scores, const int* __restrict__ idxp,
    float* __restrict__ out) {
  unsigned g = blockIdx.x * FILL_TPB + threadIdx.x;
  int idx = *idxp;
  vf4* outv = (vf4*)out;
  for (; g < TOTAL_F4; g += (unsigned)FILL_BLOCKS * FILL_TPB) {
    unsigned p = g << 2;  // flat float index of component 0
    unsigned q = p >> 18;
    int rem = (int)p - (int)((q << 18) + q);
    int row = (int)q;
    if (rem < 0) { row -= 1; rem += ROWSTRIDE; }
    float s = scores[row];
    float sm = s * MASK_VAL;
    vf4 val;
    {
      float v = (((rem - 1) & 511) == idx) ? sm : s;
      val.x = (rem == 0) ? s : v;
    }
    rem++;
    if (rem == ROWSTRIDE) { rem = 0; row++; s = scores[row]; sm = s * MASK_VAL; }
    {
      float v = (((rem - 1) & 511) == idx) ? sm : s;
      val.y = (rem == 0) ? s : v;
    }
    rem++;
    if (rem == ROWSTRIDE) { rem = 0; row++; s = scores[row]; sm = s * MASK_VAL; }
    {
      float v = (((rem - 1) & 511) == idx) ? sm : s;
      val.z = (rem == 0) ? s : v;
    }
    rem++;
    if (rem == ROWSTRIDE) { rem = 0; row++; s = scores[row]; sm = s * MASK_VAL; }
    {
      float v = (((rem - 1) & 511) == idx) ? sm : s;
      val.w = (rem == 0) ? s : v;
    }
    outv[g] = val;
  }
}

extern "C" void kernel_launch(void* const* d_in, const int* in_sizes, int n_in,
                              void* d_out, int out_size, void* d_ws,
                              size_t ws_size, hipStream_t stream) {
  const float* x = (const float*)d_in[0];
  const float* W = (const float*)d_in[1];
  const float* b = (const float*)d_in[2];
  float* out = (float*)d_out;

  float* scores = (float*)d_ws;              // 512 floats
  int* idx = (int*)((float*)d_ws + TRACKS);  // 1 int

  scores_kernel<<<TRACKS, 64, 0, stream>>>(x, W, b, scores);
  argmax_edges_kernel<<<1, TRACKS, 0, stream>>>(scores, idx, out);
  // 3x flat fill: idempotent; extra 2 dispatches exist only to measure
  // fill_flat duration via (dur - 438.3)/3.
  fill_flat<<<FILL_BLOCKS, FILL_TPB, 0, stream>>>(scores, idx, out);
  fill_flat<<<FILL_BLOCKS, FILL_TPB, 0, stream>>>(scores, idx, out);
  fill_flat<<<FILL_BLOCKS, FILL_TPB, 0, stream>>>(scores, idx, out);
}

// Round 6
// 512.377 us; speedup vs baseline: 1.4661x; 1.3560x over previous
//
#include <hip/hip_runtime.h>

// ExplodedLogit: out (512, 1 + 512*512) fp32.
//   scores = x @ W.T + b            (512,)
//   idx    = argmax(scores)
//   out[i][0]             = scores[i]
//   out[i][1 + r*512 + j] = scores[i] * (j==idx ? MASK_VAL : 1.0f)
//
// R9 == R4's kernel, adopted as final. Within-probe measurements (R7/R8
// triple-fill deltas) established:
//   flat grid-stride fill  = 85.5 us = 6.28 TB/s  <- AT the copy ceiling
//   chunked "memset-like"  = 104.3 us = 5.15 TB/s
//   base without fill      = 438.3 us (343 poison fill + ~88 harness
//                            memsets/gaps + ~8 us scores/argmax)
// Corrected HW model: pure-store streams on gfx950 are fastest with a flat
// grid-stride full-buffer sweep (4 dense passes/wave); 64KB block-windowed
// chunking costs ~20%. Loop-body VALU (~45 ops/16B) is irrelevant at HBM
// rate (VALUBusy ~5%).
// Fill is within 0.3% of the 6.29 TB/s achievable ceiling -> roofline.

#define TRACKS 512
#define FEATURES 256
#define ROWSTRIDE 262145            // 1 + 512*512
#define MASK_VAL (-105.918914f)     // float32(log(1e-46))

#define TOTAL_F4 33554560u          // 512*262145/4 (exact)
#define FILL_BLOCKS 32768
#define FILL_TPB 256

typedef float vf4 __attribute__((ext_vector_type(4)));

// ---- kernel 1: one wave per row dot-product ----
__global__ __launch_bounds__(64) void scores_kernel(
    const float* __restrict__ x, const float* __restrict__ W,
    const float* __restrict__ b, float* __restrict__ scores) {
  int row = blockIdx.x;
  int lane = threadIdx.x;  // 0..63
  const float4* xr = (const float4*)(x + row * FEATURES);
  const float4* wr = (const float4*)W;
  float4 xv = xr[lane];
  float4 wv = wr[lane];
  float s = xv.x * wv.x + xv.y * wv.y + xv.z * wv.z + xv.w * wv.w;
#pragma unroll
  for (int off = 32; off; off >>= 1) s += __shfl_down(s, off);
  if (lane == 0) scores[row] = s + b[0];
}

// ---- kernel 2: argmax (first-index tie-break) ----
__global__ __launch_bounds__(512) void argmax_kernel(
    const float* __restrict__ scores, int* __restrict__ idx_out) {
  __shared__ float svals[TRACKS];
  __shared__ int sidx[TRACKS];
  int t = threadIdx.x;
  float v = scores[t];
  svals[t] = v;
  sidx[t] = t;
  __syncthreads();
  for (int off = 256; off; off >>= 1) {
    if (t < off) {
      float v2 = svals[t + off];
      int i2 = sidx[t + off];
      if (v2 > svals[t] || (v2 == svals[t] && i2 < sidx[t])) {
        svals[t] = v2;
        sidx[t] = i2;
      }
    }
    __syncthreads();
  }
  if (t == 0) idx_out[0] = sidx[0];
}

// ---- kernel 3: flat grid-stride stream-out of the whole 537 MB ----
// p = flat float index (< 2^28, fits u32). row = p / 262145 via
// q = p >> 18;  rem = p - q*(2^18+1);  if (rem<0) row=q-1, rem+=ROWSTRIDE.
// rem == 0 -> column 0 -> scores[row]
// rem >= 1 -> bulk j = (rem-1) & 511 -> scores[row] * (j==idx ? M : 1)
__global__ __launch_bounds__(FILL_TPB) void fill_flat(
    const float* __restrict__ scores, const int* __restrict__ idxp,
    float* __restrict__ out) {
  unsigned g = blockIdx.x * FILL_TPB + threadIdx.x;
  int idx = *idxp;
  vf4* outv = (vf4*)out;
  for (; g < TOTAL_F4; g += (unsigned)FILL_BLOCKS * FILL_TPB) {
    unsigned p = g << 2;  // flat float index of component 0
    unsigned q = p >> 18;
    int rem = (int)p - (int)((q << 18) + q);
    int row = (int)q;
    if (rem < 0) { row -= 1; rem += ROWSTRIDE; }
    float s = scores[row];
    float sm = s * MASK_VAL;
    vf4 val;
    {
      float v = (((rem - 1) & 511) == idx) ? sm : s;
      val.x = (rem == 0) ? s : v;
    }
    rem++;
    if (rem == ROWSTRIDE) { rem = 0; row++; s = scores[row]; sm = s * MASK_VAL; }
    {
      float v = (((rem - 1) & 511) == idx) ? sm : s;
      val.y = (rem == 0) ? s : v;
    }
    rem++;
    if (rem == ROWSTRIDE) { rem = 0; row++; s = scores[row]; sm = s * MASK_VAL; }
    {
      float v = (((rem - 1) & 511) == idx) ? sm : s;
      val.z = (rem == 0) ? s : v;
    }
    rem++;
    if (rem == ROWSTRIDE) { rem = 0; row++; s = scores[row]; sm = s * MASK_VAL; }
    {
      float v = (((rem - 1) & 511) == idx) ? sm : s;
      val.w = (rem == 0) ? s : v;
    }
    outv[g] = val;
  }
}

extern "C" void kernel_launch(void* const* d_in, const int* in_sizes, int n_in,
                              void* d_out, int out_size, void* d_ws,
                              size_t ws_size, hipStream_t stream) {
  const float* x = (const float*)d_in[0];
  const float* W = (const float*)d_in[1];
  const float* b = (const float*)d_in[2];
  float* out = (float*)d_out;

  float* scores = (float*)d_ws;              // 512 floats
  int* idx = (int*)((float*)d_ws + TRACKS);  // 1 int

  scores_kernel<<<TRACKS, 64, 0, stream>>>(x, W, b, scores);
  argmax_kernel<<<1, TRACKS, 0, stream>>>(scores, idx);
  fill_flat<<<FILL_BLOCKS, FILL_TPB, 0, stream>>>(scores, idx, out);
}